// Round 10
// baseline (223.450 us; speedup 1.0000x reference)
//
#include <hip/hip_runtime.h>
#include <stdint.h>

#define N_ROWS 8192
#define D_DIM  1024
#define QS     640.0f     // i8 quantization scale

typedef __attribute__((ext_vector_type(4))) int   i32x4;
typedef __attribute__((ext_vector_type(4))) float f32x4;

#define GLD16(gptr, lptr) __builtin_amdgcn_global_load_lds( \
    (const __attribute__((address_space(1))) void*)(gptr),  \
    (__attribute__((address_space(3))) void*)(lptr), 16, 0, 0)

__device__ __forceinline__ int q8(float v) {
    float c = fminf(fmaxf(v * QS, -127.f), 127.f);
    return (int)__builtin_rintf(c);
}

// Fused: img/txt -> int8 (scale QS), exact fp32 diag, zero-init of sums.
// One block per row; each thread quantizes one float4 of each input.
__global__ void preprocess_kernel(const float* __restrict__ img,
                                  const float* __restrict__ txt,
                                  const float* __restrict__ scale_p,
                                  int* __restrict__ imgq,
                                  int* __restrict__ txtq,
                                  float* __restrict__ diag,
                                  float* __restrict__ row_sum,
                                  float* __restrict__ col_sum) {
    const int row = blockIdx.x;
    const int tid = threadIdx.x;

    const float4 x = ((const float4*)(img + (size_t)row * D_DIM))[tid];
    const float4 y = ((const float4*)(txt + (size_t)row * D_DIM))[tid];

    const int pi = (q8(x.x) & 0xFF) | ((q8(x.y) & 0xFF) << 8) |
                   ((q8(x.z) & 0xFF) << 16) | (q8(x.w) << 24);
    const int pt = (q8(y.x) & 0xFF) | ((q8(y.y) & 0xFF) << 8) |
                   ((q8(y.z) & 0xFF) << 16) | (q8(y.w) << 24);
    imgq[(size_t)row * 256 + tid] = pi;
    txtq[(size_t)row * 256 + tid] = pt;

    float s = x.x * y.x + x.y * y.y + x.z * y.z + x.w * y.w;
#pragma unroll
    for (int m = 1; m < 64; m <<= 1) s += __shfl_xor(s, m);
    __shared__ float ws[4];
    if ((tid & 63) == 0) ws[tid >> 6] = s;
    __syncthreads();
    if (tid == 0) {
        diag[row]    = (ws[0] + ws[1] + ws[2] + ws[3]) * (*scale_p);
        row_sum[row] = 0.f;
        col_sum[row] = 0.f;
    }
}

// R9 kernel scaled to 256x128 tile, 8 waves (4M x 2N); per-wave shape
// (64x64 output, 4x4 acc, frag addressing, XOR swizzle, staging lane-map)
// is byte-identical to the verified R9/R6 pattern -> conflict-free.
// LDS 48KB (A 32K + B 16K) -> 3 blocks/CU = 24 waves/CU (2x R9's TLP);
// staging per MFMA drops 25%.
__global__ void gemm_exp_kernel(const char* __restrict__ A,   // img i8
                                const char* __restrict__ B,   // txt i8
                                const float* __restrict__ scale_p,
                                float* __restrict__ row_sum,
                                float* __restrict__ col_sum) {
    __shared__ __align__(16) char As[256 * 128];   // 32 KB
    __shared__ __align__(16) char Bs[128 * 128];   // 16 KB

    const float dq = (*scale_p) * (1.44269504088896340736f / (QS * QS));

    const int tid  = threadIdx.x;
    const int lane = tid & 63;
    const int w    = tid >> 6;      // wave 0..7
    const int wm   = w >> 1;        // wave row (0..3), 64 rows each
    const int wn   = w & 1;         // wave col (0..1), 64 cols each
    const int ti   = blockIdx.y * 256;
    const int tj   = blockIdx.x * 128;

    const int quad = lane >> 4;
    const int l15  = lane & 15;

    // staging: lane -> (row-within-chunk, swizzled 16B k-chunk)  [== R9]
    const int srow = lane >> 3;               // 0..7
    const int sg   = (lane & 7) ^ srow;       // global 16B k-chunk after XOR swizzle

    i32x4 acc[4][4];
#pragma unroll
    for (int i = 0; i < 4; i++)
#pragma unroll
        for (int j = 0; j < 4; j++) acc[i][j] = (i32x4){0, 0, 0, 0};

    const int arow = wm * 64 + l15;   // + fr*16 -> LDS row for a-frag (0..255)
    const int brow = wn * 64 + l15;   // + fc*16 -> LDS row for b-frag (0..127)

    for (int k0 = 0; k0 < D_DIM; k0 += 128) {     // 128 i8 per LDS tile row
        // ---- stage A (32 KB-chunks: 4/wave), B (16 KB-chunks: 2/wave) ----
#pragma unroll
        for (int c = 0; c < 4; c++) {
            const int ch = w * 4 + c;             // 0..31, wave-uniform
            const int r  = ch * 8 + srow;         // tile row 0..255
            const char* ga = A + (size_t)(ti + r) * D_DIM + k0 + sg * 16;
            GLD16(ga, As + ch * 1024);
        }
#pragma unroll
        for (int c = 0; c < 2; c++) {
            const int ch = w * 2 + c;             // 0..15, wave-uniform
            const int r  = ch * 8 + srow;         // tile row 0..127
            const char* gb = B + (size_t)(tj + r) * D_DIM + k0 + sg * 16;
            GLD16(gb, Bs + ch * 1024);
        }
        __syncthreads();
        // ---- compute: 2 kk of K=64; 16 MFMA each ----
#pragma unroll
        for (int kk = 0; kk < 2; kk++) {
            i32x4 af[4], bfb[4];
#pragma unroll
            for (int fr = 0; fr < 4; fr++) {
                const int row = arow + fr * 16;
                const int kc  = ((kk << 2) + quad) ^ (row & 7);
                af[fr] = *(const i32x4*)(As + row * 128 + kc * 16);
            }
#pragma unroll
            for (int fc = 0; fc < 4; fc++) {
                const int row = brow + fc * 16;
                const int kc  = ((kk << 2) + quad) ^ (row & 7);
                bfb[fc] = *(const i32x4*)(Bs + row * 128 + kc * 16);
            }
#pragma unroll
            for (int fr = 0; fr < 4; fr++)
#pragma unroll
                for (int fc = 0; fc < 4; fc++)
                    acc[fr][fc] = __builtin_amdgcn_mfma_i32_16x16x64_i8(
                        af[fr], bfb[fc], acc[fr][fc], 0, 0, 0);
        }
        __syncthreads();
    }

    // ---- epilogue: e = 2^(acc*dq), then row/col reductions ----
    float e[4][4][4];
#pragma unroll
    for (int fr = 0; fr < 4; fr++)
#pragma unroll
        for (int fc = 0; fc < 4; fc++)
#pragma unroll
            for (int r = 0; r < 4; r++)
                e[fr][fc][r] = __builtin_amdgcn_exp2f((float)acc[fr][fc][r] * dq);

    // element (fr,fc,r) = logits[ti + wm*64 + fr*16 + quad*4 + r][tj + wn*64 + fc*16 + l15]
    const int rowbase = ti + wm * 64;
#pragma unroll
    for (int fr = 0; fr < 4; fr++) {
#pragma unroll
        for (int r = 0; r < 4; r++) {
            float s = e[fr][0][r] + e[fr][1][r] + e[fr][2][r] + e[fr][3][r];
            s += __shfl_xor(s, 1);
            s += __shfl_xor(s, 2);
            s += __shfl_xor(s, 4);
            s += __shfl_xor(s, 8);
            if (l15 == 0)
                atomicAdd(&row_sum[rowbase + fr * 16 + quad * 4 + r], s);
        }
    }

    const int colbase = tj + wn * 64;
#pragma unroll
    for (int fc = 0; fc < 4; fc++) {
        float s = 0.f;
#pragma unroll
        for (int fr = 0; fr < 4; fr++)
#pragma unroll
            for (int r = 0; r < 4; r++) s += e[fr][fc][r];
        s += __shfl_xor(s, 16);
        s += __shfl_xor(s, 32);
        if (quad == 0)
            atomicAdd(&col_sum[colbase + fc * 16 + l15], s);
    }
}

__global__ void finish_kernel(const float* __restrict__ rs, const float* __restrict__ cs,
                              const float* __restrict__ diag, float* __restrict__ out) {
    const int tid  = threadIdx.x;
    const int lane = tid & 63;
    const int w    = tid >> 6;
    float s = 0.f;
    for (int i = tid; i < N_ROWS; i += 256)
        s += logf(rs[i]) + logf(cs[i]) - 2.0f * diag[i];
#pragma unroll
    for (int m = 1; m < 64; m <<= 1) s += __shfl_xor(s, m);
    __shared__ float wsum[4];
    if (lane == 0) wsum[w] = s;
    __syncthreads();
    if (tid == 0)
        out[0] = (wsum[0] + wsum[1] + wsum[2] + wsum[3]) * (0.5f / (float)N_ROWS);
}

extern "C" void kernel_launch(void* const* d_in, const int* in_sizes, int n_in,
                              void* d_out, int out_size, void* d_ws, size_t ws_size,
                              hipStream_t stream) {
    const float* img     = (const float*)d_in[0];
    const float* txt     = (const float*)d_in[1];
    const float* scale_p = (const float*)d_in[2];
    float* out = (float*)d_out;

    char* ws = (char*)d_ws;
    int*   imgq    = (int*)ws;                                    // 8 MB
    int*   txtq    = (int*)(ws + (size_t)8 * 1024 * 1024);        // 8 MB
    float* row_sum = (float*)(ws + (size_t)16 * 1024 * 1024);     // 32 KB
    float* col_sum = row_sum + N_ROWS;                            // 32 KB
    float* diag    = col_sum + N_ROWS;                            // 32 KB

    preprocess_kernel<<<N_ROWS, 256, 0, stream>>>(img, txt, scale_p, imgq, txtq,
                                                  diag, row_sum, col_sum);

    dim3 grid(N_ROWS / 128, N_ROWS / 256);
    gemm_exp_kernel<<<grid, 512, 0, stream>>>((const char*)imgq, (const char*)txtq,
                                              scale_p, row_sum, col_sum);

    finish_kernel<<<1, 256, 0, stream>>>(row_sum, col_sum, diag, out);
}